// Round 2
// baseline (1054.797 us; speedup 1.0000x reference)
//
#include <hip/hip_runtime.h>
#include <hip/hip_fp16.h>

#define C_    15
#define H_    256
#define O_    512
#define T_    60
#define B_    1024
#define G3H_  768
#define TS    16
#define MAXG  12
#define NSLOT 96
#define NU    80          // packed 16-col units per camera: 48 gh + 32 out

typedef __attribute__((ext_vector_type(8))) short bf16x8;
typedef __attribute__((ext_vector_type(4))) float f32x4;

__device__ __forceinline__ unsigned short f2bf(float f) {
    union { float f; unsigned u; } v; v.f = f;
    return (unsigned short)((v.u + 0x7FFFu + ((v.u >> 16) & 1u)) >> 16);   // RTNE
}
__device__ __forceinline__ float sigf(float x) { return 1.f / (1.f + __expf(-x)); }

// ---------------- sort: camera grouping, XCD-pinned 16-row tile table ----------------
__global__ __launch_bounds__(256) void sort_kernel(const int* __restrict__ cam,
    int* __restrict__ order, int* __restrict__ tcam, int* __restrict__ toff,
    int* __restrict__ tcnt)
{
    __shared__ int cnt[C_], start[C_], fill[C_];
    int tid = threadIdx.x;
    if (tid < C_) cnt[tid] = 0;
    if (tid < NSLOT) { tcam[tid] = -1; toff[tid] = 0; tcnt[tid] = 0; }
    __syncthreads();
    for (int b = tid; b < B_; b += 256) atomicAdd(&cnt[cam[b]], 1);
    __syncthreads();
    if (tid == 0) {
        int run = 0;
        for (int c = 0; c < C_; ++c) { start[c] = run; fill[c] = run; run += cnt[c]; }
    }
    __syncthreads();
    for (int b = tid; b < B_; b += 256) {
        int pos = atomicAdd(&fill[cam[b]], 1);
        order[pos] = b;
    }
    __syncthreads();
    if (tid == 0) {
        int gcnt[8] = {0,0,0,0,0,0,0,0};
        for (int c = 0; c < C_; ++c) gcnt[c & 7] += (cnt[c] + TS - 1) / TS;
        int maxg = 0;
        for (int g = 0; g < 8; ++g) maxg = max(maxg, gcnt[g]);
        if (maxg <= MAXG) {
            // camera c tiles land on slots ≡ (c&7) mod 8 -> stable XCD -> weights L2-resident
            for (int g = 0; g < 8; ++g) {
                int k = 0;
                for (int c = g; c < C_; c += 8)
                    for (int r = 0; r < cnt[c]; r += TS) {
                        int slot = g + 8 * k;
                        tcam[slot] = c; toff[slot] = start[c] + r;
                        tcnt[slot] = min(TS, cnt[c] - r); ++k;
                    }
            }
        } else {
            int ti = 0;
            for (int c = 0; c < C_; ++c)
                for (int r = 0; r < cnt[c]; r += TS) {
                    tcam[ti] = c; toff[ti] = start[c] + r;
                    tcnt[ti] = min(TS, cnt[c] - r); ++ti;
                }
        }
    }
}

// ---------------- fp32 -> bf16 row-major (Wih for gi kernel) ----------------
__global__ __launch_bounds__(256) void cvt_kernel(const float* __restrict__ src,
    unsigned short* __restrict__ dst, int n4)
{
    int i = blockIdx.x * 256 + threadIdx.x;
    if (i < n4) {
        float4 v = ((const float4*)src)[i];
        unsigned p0 = (unsigned)f2bf(v.x) | ((unsigned)f2bf(v.y) << 16);
        unsigned p1 = (unsigned)f2bf(v.z) | ((unsigned)f2bf(v.w) << 16);
        ((uint2*)dst)[i] = make_uint2(p0, p1);
    }
}

// ---------------- pack Whh|Wc -> bf16 in exact B-fragment order ----------------
__global__ __launch_bounds__(64) void pack_kernel(
    const float* __restrict__ Whh, const float* __restrict__ Wc,
    unsigned short* __restrict__ Wpack)
{
    int cu = blockIdx.x;               // c*NU + u
    int c = cu / NU, u = cu - c * NU;
    int lane = threadIdx.x, q = lane >> 4, l16 = lane & 15;
    const float* src = (u < 48)
        ? &Whh[((size_t)c * G3H_ + u * 16 + l16) * H_]
        : &Wc[((size_t)c * O_ + (u - 48) * 16 + l16) * H_];
    unsigned short* dst = Wpack + ((size_t)cu * 8) * 512 + lane * 8;
#pragma unroll
    for (int kk = 0; kk < 8; ++kk) {
        float4 v0 = *(const float4*)&src[kk * 32 + q * 8];
        float4 v1 = *(const float4*)&src[kk * 32 + q * 8 + 4];
        unsigned short* d = dst + kk * 512;
        d[0] = f2bf(v0.x); d[1] = f2bf(v0.y); d[2] = f2bf(v0.z); d[3] = f2bf(v0.w);
        d[4] = f2bf(v1.x); d[5] = f2bf(v1.y); d[6] = f2bf(v1.z); d[7] = f2bf(v1.w);
    }
}

// ---------------- gi = x*Wih^T + b_ih + b_hh(r,z) via MFMA, SLOT-SORTED output ----------------
__global__ __launch_bounds__(384) void gi_mfma(
    const float* __restrict__ x, const unsigned short* __restrict__ Wih_b,
    const float* __restrict__ bih, const float* __restrict__ bhh,
    const int* __restrict__ order, const int* __restrict__ tcam,
    const int* __restrict__ toff, const int* __restrict__ tcnt,
    float* __restrict__ gi)
{
    int c = tcam[blockIdx.x]; if (c < 0) return;
    int cnt = tcnt[blockIdx.x], off = toff[blockIdx.x];
    int tid = threadIdx.x;
    __shared__ unsigned short hbfs[TS * 264];
    for (int idx = tid; idx < TS * 64; idx += 384) {
        int m = idx >> 6, c4 = idx & 63;
        float4 v = make_float4(0.f, 0.f, 0.f, 0.f);
        if (m < cnt) v = *(const float4*)&x[(size_t)order[off + m] * H_ + (c4 << 2)];
        unsigned p0 = (unsigned)f2bf(v.x) | ((unsigned)f2bf(v.y) << 16);
        unsigned p1 = (unsigned)f2bf(v.z) | ((unsigned)f2bf(v.w) << 16);
        *(uint2*)&hbfs[m * 264 + (c4 << 2)] = make_uint2(p0, p1);
    }
    __syncthreads();
    int w = tid >> 6, lane = tid & 63, q = lane >> 4, l16 = lane & 15;
    f32x4 acc[2][4];
#pragma unroll
    for (int i = 0; i < 2; ++i)
#pragma unroll
        for (int nt = 0; nt < 4; ++nt) acc[i][nt] = (f32x4){0.f, 0.f, 0.f, 0.f};
    const unsigned short* bp[2];
#pragma unroll
    for (int i = 0; i < 2; ++i)
        bp[i] = Wih_b + ((size_t)c * G3H_ + (2 * w + i) * 64 + l16) * H_;
    const unsigned short* ap = &hbfs[l16 * 264 + q * 8];
#pragma unroll 2
    for (int kk = 0; kk < 8; ++kk) {
        bf16x8 a = *(const bf16x8*)(ap + kk * 32);
#pragma unroll
        for (int i = 0; i < 2; ++i)
#pragma unroll
            for (int nt = 0; nt < 4; ++nt) {
                bf16x8 b = *(const bf16x8*)(bp[i] + (size_t)nt * 16 * H_ + kk * 32 + q * 8);
                acc[i][nt] = __builtin_amdgcn_mfma_f32_16x16x32_bf16(a, b, acc[i][nt], 0, 0, 0);
            }
    }
    // write slot-sorted: gi[(slot*16+m)][col]
#pragma unroll
    for (int i = 0; i < 2; ++i) {
        int u = 2 * w + i;
#pragma unroll
        for (int nt = 0; nt < 4; ++nt) {
            int col = u * 64 + nt * 16 + l16;
            float bias = bih[c * G3H_ + col] + (col < 2 * H_ ? bhh[c * G3H_ + col] : 0.f);
#pragma unroll
            for (int r = 0; r < 4; ++r) {
                int m = q * 4 + r;
                gi[((size_t)(blockIdx.x * TS + m)) * G3H_ + col] = acc[i][nt][r] + bias;
            }
        }
    }
}

// ---------------- fused persistent recurrence + output GEMM ----------------
// 16 waves (1024 thr). Wave w owns h-cols [16w,16w+16): gh units {w,16+w,32+w} and
// out units {48+w,64+w}. gi is loop-invariant -> registers. Per step: one ds_read
// A-fragment feeds 5 MFMAs; out[t-1] computed from same fragment (h_{t} = prev h_new);
// one raw s_barrier per step (lgkmcnt only -> outT stores stay in flight).
__global__ __launch_bounds__(1024, 1) void persist_kernel(
    const unsigned short* __restrict__ Wpack, const float* __restrict__ bhh,
    const float* __restrict__ bc, const float* __restrict__ gi,
    const int* __restrict__ order, const int* __restrict__ tcam,
    const int* __restrict__ toff, const int* __restrict__ tcnt,
    unsigned short* __restrict__ outT, int direct, float* __restrict__ outp)
{
    int slot = blockIdx.x;
    int c = tcam[slot]; if (c < 0) return;
    int n = tcnt[slot], off = toff[slot];
    int tid = threadIdx.x, w = tid >> 6, lane = tid & 63, q = lane >> 4, l16 = lane & 15;

    __shared__ unsigned short hbf[2][16][264];   // double-buffered bf16 h (16.9 KB)

    // weights -> registers once
    bf16x8 wg[3][8], wo[2][8];
#pragma unroll
    for (int ii = 0; ii < 3; ++ii)
#pragma unroll
        for (int kk = 0; kk < 8; ++kk)
            wg[ii][kk] = *(const bf16x8*)(
                Wpack + (((size_t)(c * NU + ii * 16 + w)) * 8 + kk) * 512 + lane * 8);
#pragma unroll
    for (int ii = 0; ii < 2; ++ii)
#pragma unroll
        for (int kk = 0; kk < 8; ++kk)
            wo[ii][kk] = *(const bf16x8*)(
                Wpack + (((size_t)(c * NU + 48 + ii * 16 + w)) * 8 + kk) * 512 + lane * 8);

    int col = w * 16 + l16;                       // this thread's h column
    float bhn = bhh[c * G3H_ + 2 * H_ + col];
    float bcr[2];
#pragma unroll
    for (int ii = 0; ii < 2; ++ii) bcr[ii] = bc[c * O_ + (ii * 16 + w) * 16 + l16];
    int bidx[4];
#pragma unroll
    for (int r = 0; r < 4; ++r) bidx[r] = (q * 4 + r < n) ? order[off + q * 4 + r] : -1;

    // loop-invariant gi -> registers (rows q*4+r of this slot, cols col/col+256/col+512)
    float gir[4], giz[4], gin[4];
#pragma unroll
    for (int r = 0; r < 4; ++r) {
        size_t row = (size_t)(slot * TS + q * 4 + r) * G3H_;
        gir[r] = gi[row + col];
        giz[r] = gi[row + H_ + col];
        gin[r] = gi[row + 2 * H_ + col];
    }
    float hreg[4] = {0.f, 0.f, 0.f, 0.f};

    for (int s = 0; s < T_; ++s) {
        int wbuf = s & 1, rbuf = wbuf ^ 1;
        f32x4 accg0 = (f32x4){0.f,0.f,0.f,0.f}, accg1 = accg0, accg2 = accg0;
        f32x4 acco0 = accg0, acco1 = accg0;
        if (s > 0) {
#pragma unroll
            for (int kk = 0; kk < 8; ++kk) {
                bf16x8 a = *(const bf16x8*)&hbf[rbuf][l16][kk * 32 + q * 8];
                accg0 = __builtin_amdgcn_mfma_f32_16x16x32_bf16(a, wg[0][kk], accg0, 0, 0, 0);
                accg1 = __builtin_amdgcn_mfma_f32_16x16x32_bf16(a, wg[1][kk], accg1, 0, 0, 0);
                accg2 = __builtin_amdgcn_mfma_f32_16x16x32_bf16(a, wg[2][kk], accg2, 0, 0, 0);
                acco0 = __builtin_amdgcn_mfma_f32_16x16x32_bf16(a, wo[0][kk], acco0, 0, 0, 0);
                acco1 = __builtin_amdgcn_mfma_f32_16x16x32_bf16(a, wo[1][kk], acco1, 0, 0, 0);
            }
            // out for t = s-1 (h_{t+1} = h staged in hbf[rbuf])
            int t = s - 1;
#pragma unroll
            for (int ii = 0; ii < 2; ++ii) {
                int o = (ii * 16 + w) * 16 + l16;
                const f32x4& ao = ii ? acco1 : acco0;
#pragma unroll
                for (int r = 0; r < 4; ++r) {
                    if (bidx[r] >= 0) {
                        float val = sigf(ao[r] + bcr[ii]);
                        if (direct) outp[((size_t)bidx[r] * O_ + o) * T_ + t] = val;
                        else outT[((size_t)t * B_ + bidx[r]) * O_ + o] =
                                 __half_as_ushort(__float2half_rn(val));
                    }
                }
            }
        }
        // gate update, fully in registers
#pragma unroll
        for (int r = 0; r < 4; ++r) {
            float rr = sigf(gir[r] + accg0[r]);
            float zz = sigf(giz[r] + accg1[r]);
            float pre = gin[r] + rr * (accg2[r] + bhn);
            float nn = 2.f * sigf(2.f * pre) - 1.f;          // tanh
            float hn = (1.f - zz) * nn + zz * hreg[r];
            hreg[r] = hn;
            hbf[wbuf][q * 4 + r][col] = f2bf(hn);
        }
        asm volatile("s_waitcnt lgkmcnt(0)" ::: "memory");   // ds_writes visible
        __builtin_amdgcn_s_barrier();                        // no vmcnt drain
        __builtin_amdgcn_sched_barrier(0);                   // keep next ds_read below
    }
    // final out: t = T_-1 from hbf[(T_-1)&1]
    {
        const int rb = (T_ - 1) & 1;
        f32x4 acco0 = (f32x4){0.f,0.f,0.f,0.f}, acco1 = acco0;
#pragma unroll
        for (int kk = 0; kk < 8; ++kk) {
            bf16x8 a = *(const bf16x8*)&hbf[rb][l16][kk * 32 + q * 8];
            acco0 = __builtin_amdgcn_mfma_f32_16x16x32_bf16(a, wo[0][kk], acco0, 0, 0, 0);
            acco1 = __builtin_amdgcn_mfma_f32_16x16x32_bf16(a, wo[1][kk], acco1, 0, 0, 0);
        }
        int t = T_ - 1;
#pragma unroll
        for (int ii = 0; ii < 2; ++ii) {
            int o = (ii * 16 + w) * 16 + l16;
            const f32x4& ao = ii ? acco1 : acco0;
#pragma unroll
            for (int r = 0; r < 4; ++r) {
                if (bidx[r] >= 0) {
                    float val = sigf(ao[r] + bcr[ii]);
                    if (direct) outp[((size_t)bidx[r] * O_ + o) * T_ + t] = val;
                    else outT[((size_t)t * B_ + bidx[r]) * O_ + o] =
                             __half_as_ushort(__float2half_rn(val));
                }
            }
        }
    }
}

// ---------------- transpose [T][B][O] fp16 -> [B][O][T] fp32 ----------------
__global__ __launch_bounds__(256) void transpose_kernel(
    const unsigned short* __restrict__ outT, float* __restrict__ outp)
{
    int b = blockIdx.x, o0 = blockIdx.y * 64;
    __shared__ float ts[T_][65];
    int tid = threadIdx.x;
    for (int idx = tid; idx < T_ * 64; idx += 256) {
        int t = idx >> 6, o = idx & 63;
        ts[t][o] = __half2float(__ushort_as_half(outT[((size_t)t * B_ + b) * O_ + o0 + o]));
    }
    __syncthreads();
    for (int idx = tid; idx < 64 * T_; idx += 256) {
        int o = idx / T_, t = idx - o * T_;
        outp[((size_t)b * O_ + o0 + o) * T_ + t] = ts[t][o];
    }
}

extern "C" void kernel_launch(void* const* d_in, const int* in_sizes, int n_in,
                              void* d_out, int out_size, void* d_ws, size_t ws_size,
                              hipStream_t stream)
{
    const float* x   = (const float*)d_in[0];
    const int*   cam = (const int*)d_in[1];
    const float* Wih = (const float*)d_in[2];
    const float* Whh = (const float*)d_in[3];
    const float* bih = (const float*)d_in[4];
    const float* bhh = (const float*)d_in[5];
    const float* Wc  = (const float*)d_in[6];
    const float* bc  = (const float*)d_in[7];
    float* outp = (float*)d_out;

    char* w = (char*)d_ws;
    unsigned short* Wih_b = (unsigned short*)w; w += (size_t)C_ * G3H_ * H_ * 2;
    unsigned short* Wpack = (unsigned short*)w; w += (size_t)C_ * NU * 8 * 512 * 2;
    int* order = (int*)w; w += B_ * 4;
    int* tcam  = (int*)w; w += NSLOT * 4;
    int* toff  = (int*)w; w += NSLOT * 4;
    int* tcnt  = (int*)w; w += NSLOT * 4;
    float* gi  = (float*)w; w += (size_t)NSLOT * TS * G3H_ * 4;
    unsigned short* outT = (unsigned short*)w;
    size_t need = (size_t)(w - (char*)d_ws) + (size_t)T_ * B_ * O_ * 2;
    int direct = (ws_size < need) ? 1 : 0;

    sort_kernel<<<1, 256, 0, stream>>>(cam, order, tcam, toff, tcnt);
    cvt_kernel<<<(C_ * G3H_ * H_ / 4 + 255) / 256, 256, 0, stream>>>(Wih, Wih_b, C_ * G3H_ * H_ / 4);
    pack_kernel<<<C_ * NU, 64, 0, stream>>>(Whh, Wc, Wpack);
    gi_mfma<<<NSLOT, 384, 0, stream>>>(x, Wih_b, bih, bhh, order, tcam, toff, tcnt, gi);
    persist_kernel<<<NSLOT, 1024, 0, stream>>>(Wpack, bhh, bc, gi, order, tcam, toff, tcnt,
                                               outT, direct, outp);
    if (!direct)
        transpose_kernel<<<dim3(B_, O_ / 64), 256, 0, stream>>>(outT, outp);
}

// Round 3
// 439.948 us; speedup vs baseline: 2.3975x; 2.3975x over previous
//
#include <hip/hip_runtime.h>
#include <hip/hip_fp16.h>

#define C_    15
#define H_    256
#define O_    512
#define T_    60
#define B_    1024
#define G3H_  768
#define TS    16
#define MAXG  12
#define NSLOT 96
#define NU    80          // packed 16-col units per camera: 48 gh + 32 out
#define TCH   10          // t-steps per out-kernel block

typedef __attribute__((ext_vector_type(8))) short bf16x8;
typedef __attribute__((ext_vector_type(4))) float f32x4;

__device__ __forceinline__ unsigned short f2bf(float f) {
    union { float f; unsigned u; } v; v.f = f;
    return (unsigned short)((v.u + 0x7FFFu + ((v.u >> 16) & 1u)) >> 16);   // RTNE
}
__device__ __forceinline__ float sigf(float x) { return 1.f / (1.f + __expf(-x)); }

// ---------------- sort: camera grouping, XCD-pinned 16-row tile table ----------------
__global__ __launch_bounds__(256) void sort_kernel(const int* __restrict__ cam,
    int* __restrict__ order, int* __restrict__ tcam, int* __restrict__ toff,
    int* __restrict__ tcnt)
{
    __shared__ int cnt[C_], start[C_], fill[C_];
    int tid = threadIdx.x;
    if (tid < C_) cnt[tid] = 0;
    if (tid < NSLOT) { tcam[tid] = -1; toff[tid] = 0; tcnt[tid] = 0; }
    __syncthreads();
    for (int b = tid; b < B_; b += 256) atomicAdd(&cnt[cam[b]], 1);
    __syncthreads();
    if (tid == 0) {
        int run = 0;
        for (int c = 0; c < C_; ++c) { start[c] = run; fill[c] = run; run += cnt[c]; }
    }
    __syncthreads();
    for (int b = tid; b < B_; b += 256) {
        int pos = atomicAdd(&fill[cam[b]], 1);
        order[pos] = b;
    }
    __syncthreads();
    if (tid == 0) {
        int gcnt[8] = {0,0,0,0,0,0,0,0};
        for (int c = 0; c < C_; ++c) gcnt[c & 7] += (cnt[c] + TS - 1) / TS;
        int maxg = 0;
        for (int g = 0; g < 8; ++g) maxg = max(maxg, gcnt[g]);
        if (maxg <= MAXG) {
            // camera c tiles land on slots ≡ (c&7) mod 8 -> stable XCD -> weights L2-resident
            for (int g = 0; g < 8; ++g) {
                int k = 0;
                for (int c = g; c < C_; c += 8)
                    for (int r = 0; r < cnt[c]; r += TS) {
                        int slot = g + 8 * k;
                        tcam[slot] = c; toff[slot] = start[c] + r;
                        tcnt[slot] = min(TS, cnt[c] - r); ++k;
                    }
            }
        } else {
            int ti = 0;
            for (int c = 0; c < C_; ++c)
                for (int r = 0; r < cnt[c]; r += TS) {
                    tcam[ti] = c; toff[ti] = start[c] + r;
                    tcnt[ti] = min(TS, cnt[c] - r); ++ti;
                }
        }
    }
}

// ---------------- fp32 -> bf16 row-major (Wih for gi kernel) ----------------
__global__ __launch_bounds__(256) void cvt_kernel(const float* __restrict__ src,
    unsigned short* __restrict__ dst, int n4)
{
    int i = blockIdx.x * 256 + threadIdx.x;
    if (i < n4) {
        float4 v = ((const float4*)src)[i];
        unsigned p0 = (unsigned)f2bf(v.x) | ((unsigned)f2bf(v.y) << 16);
        unsigned p1 = (unsigned)f2bf(v.z) | ((unsigned)f2bf(v.w) << 16);
        ((uint2*)dst)[i] = make_uint2(p0, p1);
    }
}

// ---------------- pack Whh|Wc -> bf16 in exact B-fragment order ----------------
__global__ __launch_bounds__(64) void pack_kernel(
    const float* __restrict__ Whh, const float* __restrict__ Wc,
    unsigned short* __restrict__ Wpack)
{
    int cu = blockIdx.x;               // c*NU + u
    int c = cu / NU, u = cu - c * NU;
    int lane = threadIdx.x, q = lane >> 4, l16 = lane & 15;
    const float* src = (u < 48)
        ? &Whh[((size_t)c * G3H_ + u * 16 + l16) * H_]
        : &Wc[((size_t)c * O_ + (u - 48) * 16 + l16) * H_];
    unsigned short* dst = Wpack + ((size_t)cu * 8) * 512 + lane * 8;
#pragma unroll
    for (int kk = 0; kk < 8; ++kk) {
        float4 v0 = *(const float4*)&src[kk * 32 + q * 8];
        float4 v1 = *(const float4*)&src[kk * 32 + q * 8 + 4];
        unsigned short* d = dst + kk * 512;
        d[0] = f2bf(v0.x); d[1] = f2bf(v0.y); d[2] = f2bf(v0.z); d[3] = f2bf(v0.w);
        d[4] = f2bf(v1.x); d[5] = f2bf(v1.y); d[6] = f2bf(v1.z); d[7] = f2bf(v1.w);
    }
}

// ---------------- gi = x*Wih^T + b_ih + b_hh(r,z) via MFMA, SLOT-SORTED output ----------------
__global__ __launch_bounds__(384) void gi_mfma(
    const float* __restrict__ x, const unsigned short* __restrict__ Wih_b,
    const float* __restrict__ bih, const float* __restrict__ bhh,
    const int* __restrict__ order, const int* __restrict__ tcam,
    const int* __restrict__ toff, const int* __restrict__ tcnt,
    float* __restrict__ gi)
{
    int c = tcam[blockIdx.x]; if (c < 0) return;
    int cnt = tcnt[blockIdx.x], off = toff[blockIdx.x];
    int tid = threadIdx.x;
    __shared__ unsigned short hbfs[TS * 264];
    for (int idx = tid; idx < TS * 64; idx += 384) {
        int m = idx >> 6, c4 = idx & 63;
        float4 v = make_float4(0.f, 0.f, 0.f, 0.f);
        if (m < cnt) v = *(const float4*)&x[(size_t)order[off + m] * H_ + (c4 << 2)];
        unsigned p0 = (unsigned)f2bf(v.x) | ((unsigned)f2bf(v.y) << 16);
        unsigned p1 = (unsigned)f2bf(v.z) | ((unsigned)f2bf(v.w) << 16);
        *(uint2*)&hbfs[m * 264 + (c4 << 2)] = make_uint2(p0, p1);
    }
    __syncthreads();
    int w = tid >> 6, lane = tid & 63, q = lane >> 4, l16 = lane & 15;
    f32x4 acc[2][4];
#pragma unroll
    for (int i = 0; i < 2; ++i)
#pragma unroll
        for (int nt = 0; nt < 4; ++nt) acc[i][nt] = (f32x4){0.f, 0.f, 0.f, 0.f};
    const unsigned short* bp[2];
#pragma unroll
    for (int i = 0; i < 2; ++i)
        bp[i] = Wih_b + ((size_t)c * G3H_ + (2 * w + i) * 64 + l16) * H_;
    const unsigned short* ap = &hbfs[l16 * 264 + q * 8];
#pragma unroll 2
    for (int kk = 0; kk < 8; ++kk) {
        bf16x8 a = *(const bf16x8*)(ap + kk * 32);
#pragma unroll
        for (int i = 0; i < 2; ++i)
#pragma unroll
            for (int nt = 0; nt < 4; ++nt) {
                bf16x8 b = *(const bf16x8*)(bp[i] + (size_t)nt * 16 * H_ + kk * 32 + q * 8);
                acc[i][nt] = __builtin_amdgcn_mfma_f32_16x16x32_bf16(a, b, acc[i][nt], 0, 0, 0);
            }
    }
    // write slot-sorted: gi[(slot*16+m)][col]
#pragma unroll
    for (int i = 0; i < 2; ++i) {
        int u = 2 * w + i;
#pragma unroll
        for (int nt = 0; nt < 4; ++nt) {
            int col = u * 64 + nt * 16 + l16;
            float bias = bih[c * G3H_ + col] + (col < 2 * H_ ? bhh[c * G3H_ + col] : 0.f);
#pragma unroll
            for (int r = 0; r < 4; ++r) {
                int m = q * 4 + r;
                gi[((size_t)(blockIdx.x * TS + m)) * G3H_ + col] = acc[i][nt][r] + bias;
            }
        }
    }
}

// ---------------- persistent recurrence: in-register gate update in fragment layout ----------------
// Round-1 proven structure (128 VGPR, no spill) + raw per-step barrier: lgkmcnt-only wait
// so the 8 htraj stores/thread/step stay in flight instead of draining at __syncthreads.
__global__ __launch_bounds__(512, 2) void persist_kernel(
    const unsigned short* __restrict__ Wpack, const float* __restrict__ bhh,
    const float* __restrict__ gi, const int* __restrict__ tcam,
    unsigned short* __restrict__ htraj)
{
    int slot = blockIdx.x;
    int c = tcam[slot]; if (c < 0) return;
    int tid = threadIdx.x, w = tid >> 6, lane = tid & 63, q = lane >> 4, l16 = lane & 15;

    __shared__ float gisT[G3H_][20];             // gi transposed to fragment layout (61.4 KB)
    __shared__ unsigned short hbf[2][16][264];   // double-buffered bf16 h (16.9 KB)

    // stage gisT[col][m] = gi[(slot*16+m)*768 + col]  (coalesced global reads, one-time)
    for (int idx = tid; idx < TS * G3H_; idx += 512) {
        int m = idx / G3H_, col = idx - m * G3H_;
        gisT[col][m] = gi[((size_t)(slot * TS + m)) * G3H_ + col];
    }

    // weights -> registers once: wf[0..1]=r(cb0,cb1) wf[2..3]=z wf[4..5]=n
    bf16x8 wf[6][8];
#pragma unroll
    for (int ii = 0; ii < 3; ++ii)
#pragma unroll
        for (int jj = 0; jj < 2; ++jj)
#pragma unroll
            for (int kk = 0; kk < 8; ++kk)
                wf[ii * 2 + jj][kk] = *(const bf16x8*)(
                    Wpack + (((size_t)(c * NU + ii * 16 + w + 8 * jj)) * 8 + kk) * 512 + lane * 8);

    float bhn[2], hreg[2][4];
#pragma unroll
    for (int i = 0; i < 2; ++i) {
        int col = (w + 8 * i) * 16 + l16;
        bhn[i] = bhh[c * G3H_ + 2 * H_ + col];
#pragma unroll
        for (int r = 0; r < 4; ++r) hreg[i][r] = 0.f;
    }
    unsigned short* hp = htraj + ((size_t)slot * TS + q * 4) * 256 + w * 16 + l16;
    __syncthreads();

#pragma unroll 2
    for (int s = 0; s < T_; ++s) {
        int wbuf = s & 1, rbuf = wbuf ^ 1;
        f32x4 acc[6];
#pragma unroll
        for (int ui = 0; ui < 6; ++ui) acc[ui] = (f32x4){0.f, 0.f, 0.f, 0.f};
        if (s > 0) {
#pragma unroll
            for (int kk = 0; kk < 8; ++kk) {
                bf16x8 a = *(const bf16x8*)&hbf[rbuf][l16][kk * 32 + q * 8];
#pragma unroll
                for (int ui = 0; ui < 6; ++ui)
                    acc[ui] = __builtin_amdgcn_mfma_f32_16x16x32_bf16(a, wf[ui][kk], acc[ui], 0, 0, 0);
            }
        }
#pragma unroll
        for (int i = 0; i < 2; ++i) {
            int col = (w + 8 * i) * 16 + l16;
            f32x4 gr = *(const f32x4*)&gisT[col][q * 4];
            f32x4 gz = *(const f32x4*)&gisT[H_ + col][q * 4];
            f32x4 gn = *(const f32x4*)&gisT[2 * H_ + col][q * 4];
#pragma unroll
            for (int r = 0; r < 4; ++r) {
                float rr = sigf(gr[r] + acc[i][r]);
                float zz = sigf(gz[r] + acc[2 + i][r]);
                float pre = gn[r] + rr * (acc[4 + i][r] + bhn[i]);
                float nn = 2.f * sigf(2.f * pre) - 1.f;          // tanh
                float hn = (1.f - zz) * nn + zz * hreg[i][r];
                hreg[i][r] = hn;
                unsigned short hb = f2bf(hn);
                hbf[wbuf][q * 4 + r][col] = hb;
                hp[r * 256 + i * 128] = hb;
            }
        }
        hp += (size_t)NSLOT * TS * 256;
        asm volatile("s_waitcnt lgkmcnt(0)" ::: "memory");   // ds ops visible; htraj stores keep flying
        __builtin_amdgcn_s_barrier();
        __builtin_amdgcn_sched_barrier(0);                   // no hoisting of next ds_read above barrier
    }
}

// ---------------- out GEMM over trajectory: out[t] = sigmoid(h_{t+1} Wc^T + bc) ----------------
// Double-buffered h tile: issue global load for t+1 before MFMAs of t (T14), one raw
// barrier per ti (lgkmcnt-only -> output stores never drain inside the loop).
__global__ __launch_bounds__(512, 2) void out_kernel(
    const unsigned short* __restrict__ Wpack, const float* __restrict__ bc,
    const unsigned short* __restrict__ htraj, const int* __restrict__ order,
    const int* __restrict__ tcam, const int* __restrict__ toff,
    const int* __restrict__ tcnt, unsigned short* __restrict__ outT,
    int direct, float* __restrict__ outp)
{
    int slot = blockIdx.x;
    int c = tcam[slot]; if (c < 0) return;
    int n = tcnt[slot], off = toff[slot];
    int tid = threadIdx.x, w = tid >> 6, lane = tid & 63, q = lane >> 4, l16 = lane & 15;
    __shared__ unsigned short hb[2][16][264];
    __shared__ int ord16[16];
    if (tid < 16) ord16[tid] = (tid < n) ? order[off + tid] : -1;

    bf16x8 wf[4][8];
    const unsigned short* wb = Wpack + ((size_t)c * NU + 48 + w * 4) * 8 * 512 + lane * 8;
#pragma unroll
    for (int ui = 0; ui < 4; ++ui)
#pragma unroll
        for (int kk = 0; kk < 8; ++kk)
            wf[ui][kk] = *(const bf16x8*)(wb + ((size_t)ui * 8 + kk) * 512);
    float bcr[4];
#pragma unroll
    for (int ui = 0; ui < 4; ++ui)
        bcr[ui] = bc[c * O_ + (w * 4 + ui) * 16 + l16];

    int m = tid >> 5, c8 = (tid & 31) * 8;
    const unsigned short* hsrc =
        &htraj[(((size_t)(blockIdx.y * TCH) * NSLOT + slot) * 16 + m) * 256 + c8];
    uint4 stg = *(const uint4*)hsrc;               // tile t0
    *(uint4*)&hb[0][m][c8] = stg;
    __syncthreads();                               // ord16 + hb[0] visible

    for (int ti = 0; ti < TCH; ++ti) {
        int t = blockIdx.y * TCH + ti;
        int cur = ti & 1;
        if (ti + 1 < TCH)                          // issue next tile load early (hidden by MFMAs)
            stg = *(const uint4*)(hsrc + (size_t)(ti + 1) * NSLOT * TS * 256);
        f32x4 acc[4];
#pragma unroll
        for (int ui = 0; ui < 4; ++ui) acc[ui] = (f32x4){0.f, 0.f, 0.f, 0.f};
#pragma unroll
        for (int kk = 0; kk < 8; ++kk) {
            bf16x8 a = *(const bf16x8*)&hb[cur][l16][kk * 32 + q * 8];
#pragma unroll
            for (int ui = 0; ui < 4; ++ui)
                acc[ui] = __builtin_amdgcn_mfma_f32_16x16x32_bf16(a, wf[ui][kk], acc[ui], 0, 0, 0);
        }
#pragma unroll
        for (int ui = 0; ui < 4; ++ui) {
            int o = (w * 4 + ui) * 16 + l16;
#pragma unroll
            for (int r = 0; r < 4; ++r) {
                int b = ord16[q * 4 + r];
                if (b >= 0) {
                    float val = sigf(acc[ui][r] + bcr[ui]);
                    if (direct) outp[((size_t)b * O_ + o) * T_ + t] = val;
                    else outT[((size_t)t * B_ + b) * O_ + o] =
                             __half_as_ushort(__float2half_rn(val));
                }
            }
        }
        if (ti + 1 < TCH) {
            *(uint4*)&hb[cur ^ 1][m][c8] = stg;    // compiler inserts vmcnt wait for stg only
            asm volatile("s_waitcnt lgkmcnt(0)" ::: "memory");
            __builtin_amdgcn_s_barrier();
            __builtin_amdgcn_sched_barrier(0);
        }
    }
}

// ---------------- transpose [T][B][O] fp16 -> [B][O][T] fp32 ----------------
__global__ __launch_bounds__(256) void transpose_kernel(
    const unsigned short* __restrict__ outT, float* __restrict__ outp)
{
    int b = blockIdx.x, o0 = blockIdx.y * 64;
    __shared__ float ts[T_][65];
    int tid = threadIdx.x;
    for (int idx = tid; idx < T_ * 64; idx += 256) {
        int t = idx >> 6, o = idx & 63;
        ts[t][o] = __half2float(__ushort_as_half(outT[((size_t)t * B_ + b) * O_ + o0 + o]));
    }
    __syncthreads();
    for (int idx = tid; idx < 64 * T_; idx += 256) {
        int o = idx / T_, t = idx - o * T_;
        outp[((size_t)b * O_ + o0 + o) * T_ + t] = ts[t][o];
    }
}

extern "C" void kernel_launch(void* const* d_in, const int* in_sizes, int n_in,
                              void* d_out, int out_size, void* d_ws, size_t ws_size,
                              hipStream_t stream)
{
    const float* x   = (const float*)d_in[0];
    const int*   cam = (const int*)d_in[1];
    const float* Wih = (const float*)d_in[2];
    const float* Whh = (const float*)d_in[3];
    const float* bih = (const float*)d_in[4];
    const float* bhh = (const float*)d_in[5];
    const float* Wc  = (const float*)d_in[6];
    const float* bc  = (const float*)d_in[7];
    float* outp = (float*)d_out;

    char* w = (char*)d_ws;
    unsigned short* Wih_b = (unsigned short*)w; w += (size_t)C_ * G3H_ * H_ * 2;
    unsigned short* Wpack = (unsigned short*)w; w += (size_t)C_ * NU * 8 * 512 * 2;
    int* order = (int*)w; w += B_ * 4;
    int* tcam  = (int*)w; w += NSLOT * 4;
    int* toff  = (int*)w; w += NSLOT * 4;
    int* tcnt  = (int*)w; w += NSLOT * 4;
    float* gi  = (float*)w; w += (size_t)NSLOT * TS * G3H_ * 4;
    unsigned short* htraj = (unsigned short*)w; w += (size_t)T_ * NSLOT * 16 * 256 * 2;
    unsigned short* outT = (unsigned short*)w;
    size_t need = (size_t)(w - (char*)d_ws) + (size_t)T_ * B_ * O_ * 2;
    int direct = (ws_size < need) ? 1 : 0;

    sort_kernel<<<1, 256, 0, stream>>>(cam, order, tcam, toff, tcnt);
    cvt_kernel<<<(C_ * G3H_ * H_ / 4 + 255) / 256, 256, 0, stream>>>(Wih, Wih_b, C_ * G3H_ * H_ / 4);
    pack_kernel<<<C_ * NU, 64, 0, stream>>>(Whh, Wc, Wpack);
    gi_mfma<<<NSLOT, 384, 0, stream>>>(x, Wih_b, bih, bhh, order, tcam, toff, tcnt, gi);
    persist_kernel<<<NSLOT, 512, 0, stream>>>(Wpack, bhh, gi, tcam, htraj);
    out_kernel<<<dim3(NSLOT, T_ / TCH), 512, 0, stream>>>(Wpack, bc, htraj, order, tcam,
                                                          toff, tcnt, outT, direct, outp);
    if (!direct)
        transpose_kernel<<<dim3(B_, O_ / 64), 256, 0, stream>>>(outT, outp);
}